// Round 1
// baseline (316.814 us; speedup 1.0000x reference)
//
#include <hip/hip_runtime.h>
#include <hip/hip_bf16.h>
#include <hip/hip_fp16.h>

// Problem: B=4096, D=1024, H=8192, O=1000
//   winners[b] = argmin_h ||x_b - k_h||  (== argmax dot, since k rows unit-norm)
//   output[b,o] = G[o, winners[b]]
// Strategy: fp16 MFMA GEMM for approximate scores + per-tile top-2 epilogue,
// then exact fp64 refinement of in-margin candidates, then gather.

#define BB 4096
#define DD 1024
#define HH 8192
#define OO 1000

#define BM 128
#define BN 128
#define BK 32
#define NTILES (HH / BN)   // 64

typedef _Float16 f16;
typedef _Float16 f16x4 __attribute__((ext_vector_type(4)));
typedef _Float16 f16x8 __attribute__((ext_vector_type(8)));
typedef float f32x4 __attribute__((ext_vector_type(4)));

typedef __attribute__((address_space(3))) uint32_t lds_u32_t;
typedef __attribute__((address_space(1))) uint32_t glb_u32_t;

// ---------------- convert fp32 -> fp16 (x and k) ----------------
__global__ __launch_bounds__(256) void cvt_kernel(
    const float* __restrict__ x, const float* __restrict__ kw,
    f16* __restrict__ xh, f16* __restrict__ kh) {
  size_t i = (size_t)blockIdx.x * 256 + threadIdx.x;  // quad index
  const size_t nx4 = (size_t)BB * DD / 4;  // 1M
  const size_t nk4 = (size_t)HH * DD / 4;  // 2M
  if (i < nx4) {
    float4 v = ((const float4*)x)[i];
    f16x4 h;
    h[0] = (f16)v.x; h[1] = (f16)v.y; h[2] = (f16)v.z; h[3] = (f16)v.w;
    *(f16x4*)(xh + 4 * i) = h;
  } else if (i < nx4 + nk4) {
    size_t j = i - nx4;
    float4 v = ((const float4*)kw)[j];
    f16x4 h;
    h[0] = (f16)v.x; h[1] = (f16)v.y; h[2] = (f16)v.z; h[3] = (f16)v.w;
    *(f16x4*)(kh + 4 * j) = h;
  }
}

// merge top-2 set (u1,d1,u2,d2) into (v1,c1,v2,c2); both sorted desc
__device__ __forceinline__ void merge2(float& v1, int& c1, float& v2, int& c2,
                                       float u1, int d1, float u2, int d2) {
  if (u1 > v1) {
    float t = v1; int tc = c1;
    v1 = u1; c1 = d1;
    if (u2 > t) { v2 = u2; c2 = d2; } else { v2 = t; c2 = tc; }
  } else if (u1 > v2) {
    v2 = u1; c2 = d1;
  }
}

// ---------------- GEMM (scores) + per-row-tile top-2 ----------------
// A = xh [B][D] fp16 row-major, Bt = kh [H][D] fp16 row-major (NT layout).
// Each block: 128x128 C-tile. Epilogue: top-2 (val,col) per row over tile.
__global__ __launch_bounds__(256) void gemm_top2(
    const f16* __restrict__ A, const f16* __restrict__ Bt,
    float* __restrict__ pv, int* __restrict__ pc) {
  __shared__ __align__(16) f16 sA[BM * BK];  // 8 KB, [row][k] no pad (global_load_lds)
  __shared__ __align__(16) f16 sB[BN * BK];  // 8 KB
  __shared__ float mv[128][2][2];
  __shared__ int   mc[128][2][2];

  const int tid = threadIdx.x;
  const int w = tid >> 6;       // wave 0..3
  const int L = tid & 63;       // lane
  const int m0 = blockIdx.y * BM;
  const int n0 = blockIdx.x * BN;
  const int rm = (w >> 1) * 64;  // wave row base within tile
  const int cn = (w & 1) * 64;   // wave col base within tile

  f32x4 acc[4][4];
#pragma unroll
  for (int i = 0; i < 4; ++i)
#pragma unroll
    for (int j = 0; j < 4; ++j) {
      acc[i][j][0] = 0.f; acc[i][j][1] = 0.f; acc[i][j][2] = 0.f; acc[i][j][3] = 0.f;
    }

  const int lm = L & 15;    // fragment row/col within 16
  const int lq = L >> 4;    // quad -> k-offset lq*8

  for (int kt = 0; kt < DD / BK; ++kt) {
    __syncthreads();  // prev compute done before overwriting LDS
#pragma unroll
    for (int i = 0; i < 2; ++i) {
      int c = i * 256 + tid;     // 16B-chunk id, 0..511
      int r = c >> 2, ch = c & 3;
      const f16* gpa = A + (size_t)(m0 + r) * DD + kt * BK + ch * 8;
      __builtin_amdgcn_global_load_lds((const glb_u32_t*)gpa, (lds_u32_t*)(sA + c * 8), 16, 0, 0);
      const f16* gpb = Bt + (size_t)(n0 + r) * DD + kt * BK + ch * 8;
      __builtin_amdgcn_global_load_lds((const glb_u32_t*)gpb, (lds_u32_t*)(sB + c * 8), 16, 0, 0);
    }
    __syncthreads();  // drains vmcnt (compiler emits waitcnt before s_barrier)

    f16x8 af[4], bf[4];
#pragma unroll
    for (int i = 0; i < 4; ++i)
      af[i] = *(const f16x8*)(sA + (rm + i * 16 + lm) * BK + lq * 8);
#pragma unroll
    for (int j = 0; j < 4; ++j)
      bf[j] = *(const f16x8*)(sB + (cn + j * 16 + lm) * BK + lq * 8);
#pragma unroll
    for (int i = 0; i < 4; ++i)
#pragma unroll
      for (int j = 0; j < 4; ++j)
        acc[i][j] = __builtin_amdgcn_mfma_f32_16x16x32_f16(af[i], bf[j], acc[i][j], 0, 0, 0);
  }

  // Epilogue: per-row top-2 over this block's 128 columns.
  // C/D layout (16x16x32): col = lane&15, row = (lane>>4)*4 + reg.
  const int colbase = n0 + cn + lm;
#pragma unroll
  for (int i = 0; i < 4; ++i) {
#pragma unroll
    for (int r = 0; r < 4; ++r) {
      float v1 = -1e30f, v2 = -1e30f; int c1 = 0, c2 = 0;
#pragma unroll
      for (int j = 0; j < 4; ++j) {
        float v = acc[i][j][r];
        int c = colbase + j * 16;
        if (v > v1) { v2 = v1; c2 = c1; v1 = v; c1 = c; }
        else if (v > v2) { v2 = v; c2 = c; }
      }
      // butterfly across the 16 lanes holding the 16 columns of this row
#pragma unroll
      for (int msk = 1; msk < 16; msk <<= 1) {
        float u1 = __shfl_xor(v1, msk, 64);
        int   d1 = __shfl_xor(c1, msk, 64);
        float u2 = __shfl_xor(v2, msk, 64);
        int   d2 = __shfl_xor(c2, msk, 64);
        merge2(v1, c1, v2, c2, u1, d1, u2, d2);
      }
      if (lm == 0) {
        int rl = rm + i * 16 + lq * 4 + r;  // row within tile 0..127
        mv[rl][w & 1][0] = v1; mc[rl][w & 1][0] = c1;
        mv[rl][w & 1][1] = v2; mc[rl][w & 1][1] = c2;
      }
    }
  }
  __syncthreads();
  if (tid < 128) {
    float v1 = mv[tid][0][0]; int c1 = mc[tid][0][0];
    float v2 = mv[tid][0][1]; int c2 = mc[tid][0][1];
    merge2(v1, c1, v2, c2, mv[tid][1][0], mc[tid][1][0], mv[tid][1][1], mc[tid][1][1]);
    size_t base = ((size_t)(m0 + tid) * NTILES + blockIdx.x) * 2;
    pv[base] = v1; pc[base] = c1;
    pv[base + 1] = v2; pc[base + 1] = c2;
  }
}

// ---------------- exact fp64 refinement + winner select ----------------
__global__ __launch_bounds__(256) void select_kernel(
    const float* __restrict__ x, const float* __restrict__ kw,
    const float* __restrict__ pv, const int* __restrict__ pc,
    float* __restrict__ out_w, int* __restrict__ winners) {
  const int b = blockIdx.x;
  const int tid = threadIdx.x;
  __shared__ float sv[2 * NTILES];
  __shared__ int   sc[2 * NTILES];
  __shared__ double sredA[4], sredB[4];
  __shared__ double s_x2;
  __shared__ float s_M;
  __shared__ double s_best;
  __shared__ int s_bestc;

  if (tid < 2 * NTILES) {
    sv[tid] = pv[(size_t)b * 2 * NTILES + tid];
    sc[tid] = pc[(size_t)b * 2 * NTILES + tid];
  }

  // x2 in fp64
  double x2 = 0.0;
  for (int d = tid; d < DD; d += 256) {
    double xv = (double)x[(size_t)b * DD + d];
    x2 += xv * xv;
  }
#pragma unroll
  for (int o = 32; o >= 1; o >>= 1) x2 += __shfl_down(x2, o, 64);
  if ((tid & 63) == 0) sredA[tid >> 6] = x2;
  __syncthreads();
  if (tid == 0) {
    s_x2 = sredA[0] + sredA[1] + sredA[2] + sredA[3];
    float M = -1e30f;
    for (int e = 0; e < 2 * NTILES; ++e) M = fmaxf(M, sv[e]);
    s_M = M;
    s_best = 1e300;
    s_bestc = 0x7fffffff;
  }
  __syncthreads();

  const float thr = s_M - 0.01f;  // margin >> fp16-dot error (rms ~4e-4)
  for (int e = 0; e < 2 * NTILES; ++e) {
    if (sv[e] < thr) continue;  // block-uniform (LDS value)
    int col = sc[e];
    double dot = 0.0, w2 = 0.0;
    for (int d = tid; d < DD; d += 256) {
      double wv = (double)kw[(size_t)col * DD + d];
      double xv = (double)x[(size_t)b * DD + d];
      dot += xv * wv;
      w2 += wv * wv;
    }
#pragma unroll
    for (int o = 32; o >= 1; o >>= 1) {
      dot += __shfl_down(dot, o, 64);
      w2 += __shfl_down(w2, o, 64);
    }
    if ((tid & 63) == 0) { sredA[tid >> 6] = dot; sredB[tid >> 6] = w2; }
    __syncthreads();
    if (tid == 0) {
      double dsum = sredA[0] + sredA[1] + sredA[2] + sredA[3];
      double wsum = sredB[0] + sredB[1] + sredB[2] + sredB[3];
      double sq = s_x2 + wsum - 2.0 * dsum;
      if (sq < s_best || (sq == s_best && col < s_bestc)) {
        s_best = sq;
        s_bestc = col;
      }
    }
    __syncthreads();
  }
  if (tid == 0) {
    out_w[b] = (float)s_bestc;  // winners as fp32 values (harness reads flat fp32)
    winners[b] = s_bestc;
  }
}

// ---------------- gather: out[b,o] = G[o*H + w_b] ----------------
__global__ __launch_bounds__(256) void gather_kernel(
    const float* __restrict__ G, const int* __restrict__ winners,
    float* __restrict__ out) {
  const int b = blockIdx.y;
  const int o = blockIdx.x * 256 + threadIdx.x;
  if (o < OO) {
    int w = winners[b];  // broadcast load
    out[(size_t)b * OO + o] = G[(size_t)o * HH + w];
  }
}

extern "C" void kernel_launch(void* const* d_in, const int* in_sizes, int n_in,
                              void* d_out, int out_size, void* d_ws, size_t ws_size,
                              hipStream_t stream) {
  const float* x  = (const float*)d_in[0];  // [4096][1024]
  const float* kw = (const float*)d_in[1];  // [8192][1024]
  const float* gw = (const float*)d_in[2];  // [1000][8192]
  float* out = (float*)d_out;               // [4096*1000] output ++ [4096] winners

  // workspace layout (needs ~28 MB)
  char* ws = (char*)d_ws;
  f16*   xh      = (f16*)(ws);                          // 8 MB
  f16*   kh      = (f16*)(ws + (size_t)8 * 1024 * 1024);  // 16 MB
  float* pv      = (float*)(ws + (size_t)24 * 1024 * 1024); // 2 MB
  int*   pc      = (int*)(ws + (size_t)26 * 1024 * 1024);   // 2 MB
  int*   winners = (int*)(ws + (size_t)28 * 1024 * 1024);   // 16 KB

  // 1) fp32 -> fp16
  int cvt_blocks = (int)(((size_t)BB * DD / 4 + (size_t)HH * DD / 4 + 255) / 256);
  cvt_kernel<<<cvt_blocks, 256, 0, stream>>>(x, kw, xh, kh);

  // 2) fp16 MFMA GEMM + per-tile top-2
  dim3 g(HH / BN, BB / BM);  // (64, 32)
  gemm_top2<<<g, 256, 0, stream>>>(xh, kh, pv, pc);

  // 3) exact fp64 refinement -> winners
  select_kernel<<<BB, 256, 0, stream>>>(x, kw, pv, pc, out + (size_t)BB * OO, winners);

  // 4) gather output rows
  gather_kernel<<<dim3((OO + 255) / 256, BB), 256, 0, stream>>>(gw, winners, out);
}

// Round 2
// 289.634 us; speedup vs baseline: 1.0938x; 1.0938x over previous
//
#include <hip/hip_runtime.h>
#include <hip/hip_bf16.h>
#include <hip/hip_fp16.h>

// Problem: B=4096, D=1024, H=8192, O=1000
//   winners[b] = argmin_h ||x_b - k_h||  (== argmax dot, k rows unit-norm)
//   output[b,o] = G[o, winners[b]]
// Strategy: fp16 MFMA GEMM (XOR-swizzled LDS, conflict-free ds_read_b128)
// + per-tile top-2 epilogue, exact fp64 refinement, transpose+coalesced gather.

#define BB 4096
#define DD 1024
#define HH 8192
#define OO 1000

#define BM 128
#define BN 128
#define BK 32
#define NTILES (HH / BN)   // 64

typedef _Float16 f16;
typedef _Float16 f16x4 __attribute__((ext_vector_type(4)));
typedef _Float16 f16x8 __attribute__((ext_vector_type(8)));
typedef float f32x4 __attribute__((ext_vector_type(4)));

typedef __attribute__((address_space(3))) uint32_t lds_u32_t;
typedef __attribute__((address_space(1))) uint32_t glb_u32_t;

// ---------------- convert fp32 -> fp16 (x and k) ----------------
__global__ __launch_bounds__(256) void cvt_kernel(
    const float* __restrict__ x, const float* __restrict__ kw,
    f16* __restrict__ xh, f16* __restrict__ kh) {
  size_t i = (size_t)blockIdx.x * 256 + threadIdx.x;  // quad index
  const size_t nx4 = (size_t)BB * DD / 4;  // 1M
  const size_t nk4 = (size_t)HH * DD / 4;  // 2M
  if (i < nx4) {
    float4 v = ((const float4*)x)[i];
    f16x4 h;
    h[0] = (f16)v.x; h[1] = (f16)v.y; h[2] = (f16)v.z; h[3] = (f16)v.w;
    *(f16x4*)(xh + 4 * i) = h;
  } else if (i < nx4 + nk4) {
    size_t j = i - nx4;
    float4 v = ((const float4*)kw)[j];
    f16x4 h;
    h[0] = (f16)v.x; h[1] = (f16)v.y; h[2] = (f16)v.z; h[3] = (f16)v.w;
    *(f16x4*)(kh + 4 * j) = h;
  }
}

// merge top-2 set (u1,d1,u2,d2) into (v1,c1,v2,c2); both sorted desc
__device__ __forceinline__ void merge2(float& v1, int& c1, float& v2, int& c2,
                                       float u1, int d1, float u2, int d2) {
  if (u1 > v1) {
    float t = v1; int tc = c1;
    v1 = u1; c1 = d1;
    if (u2 > t) { v2 = u2; c2 = d2; } else { v2 = t; c2 = tc; }
  } else if (u1 > v2) {
    v2 = u1; c2 = d1;
  }
}

// ---------------- GEMM (scores) + per-row-tile top-2 ----------------
// A = xh [B][D] fp16, Bt = kh [H][D] fp16 (NT layout). Block: 128x128 C-tile.
// LDS layout is XOR-swizzled per 16B chunk: LDS chunk (row, ch) holds global
// chunk (row, ch ^ (row&3)). Writers (global_load_lds, lane-linear LDS dst)
// permute their SOURCE address; readers use ch = lq ^ (row&3). This spreads
// the ds_read_b128 fragment reads evenly over all 32 banks (conflict-free)
// vs the linear layout's 2x serialization.
__global__ __launch_bounds__(256) void gemm_top2(
    const f16* __restrict__ A, const f16* __restrict__ Bt,
    float* __restrict__ pv, int* __restrict__ pc) {
  __shared__ __align__(16) f16 sA[BM * BK];  // 8 KB
  __shared__ __align__(16) f16 sB[BN * BK];  // 8 KB
  __shared__ float mv[128][2][2];
  __shared__ int   mc[128][2][2];

  const int tid = threadIdx.x;
  const int w = tid >> 6;       // wave 0..3
  const int L = tid & 63;       // lane
  const int m0 = blockIdx.y * BM;
  const int n0 = blockIdx.x * BN;
  const int rm = (w >> 1) * 64;  // wave row base within tile
  const int cn = (w & 1) * 64;   // wave col base within tile

  f32x4 acc[4][4];
#pragma unroll
  for (int i = 0; i < 4; ++i)
#pragma unroll
    for (int j = 0; j < 4; ++j) {
      acc[i][j][0] = 0.f; acc[i][j][1] = 0.f; acc[i][j][2] = 0.f; acc[i][j][3] = 0.f;
    }

  const int lm = L & 15;    // fragment row within 16
  const int lq = L >> 4;    // quad -> k-offset lq*8

  // staging: thread owns chunks c0=tid, c1=tid+256 (chunk = 16B = 8 f16)
  const int c0 = tid, c1 = tid + 256;
  const int r0 = c0 >> 2, r1 = c1 >> 2;
  const int s0 = ((c0 & 3) ^ (r0 & 3)) * 8;  // swizzled source k-offset (f16)
  const int s1 = ((c1 & 3) ^ (r1 & 3)) * 8;
  const f16* pA0 = A + (size_t)(m0 + r0) * DD + s0;
  const f16* pA1 = A + (size_t)(m0 + r1) * DD + s1;
  const f16* pB0 = Bt + (size_t)(n0 + r0) * DD + s0;
  const f16* pB1 = Bt + (size_t)(n0 + r1) * DD + s1;

  // fragment read bases (halves): row*BK + (lq ^ (row&3))*8; row&3 == lm&3
  const int ra = (rm + lm) * BK + ((lq ^ (lm & 3)) * 8);
  const int rb = (cn + lm) * BK + ((lq ^ (lm & 3)) * 8);

  for (int kt = 0; kt < DD / BK; ++kt) {
    __syncthreads();  // prev compute done before overwriting LDS
    __builtin_amdgcn_global_load_lds((const glb_u32_t*)pA0, (lds_u32_t*)(sA + c0 * 8), 16, 0, 0);
    __builtin_amdgcn_global_load_lds((const glb_u32_t*)pA1, (lds_u32_t*)(sA + c1 * 8), 16, 0, 0);
    __builtin_amdgcn_global_load_lds((const glb_u32_t*)pB0, (lds_u32_t*)(sB + c0 * 8), 16, 0, 0);
    __builtin_amdgcn_global_load_lds((const glb_u32_t*)pB1, (lds_u32_t*)(sB + c1 * 8), 16, 0, 0);
    pA0 += BK; pA1 += BK; pB0 += BK; pB1 += BK;
    __syncthreads();  // drains vmcnt before use

    f16x8 af[4], bf[4];
#pragma unroll
    for (int i = 0; i < 4; ++i)
      af[i] = *(const f16x8*)(sA + ra + i * 16 * BK);
#pragma unroll
    for (int j = 0; j < 4; ++j)
      bf[j] = *(const f16x8*)(sB + rb + j * 16 * BK);
#pragma unroll
    for (int i = 0; i < 4; ++i)
#pragma unroll
      for (int j = 0; j < 4; ++j)
        acc[i][j] = __builtin_amdgcn_mfma_f32_16x16x32_f16(af[i], bf[j], acc[i][j], 0, 0, 0);
  }

  // Epilogue: per-row top-2 over this block's 128 columns.
  // C/D layout (16x16x32): col = lane&15, row = (lane>>4)*4 + reg.
  const int colbase = n0 + cn + lm;
#pragma unroll
  for (int i = 0; i < 4; ++i) {
#pragma unroll
    for (int r = 0; r < 4; ++r) {
      float v1 = -1e30f, v2 = -1e30f; int c1_ = 0, c2 = 0;
#pragma unroll
      for (int j = 0; j < 4; ++j) {
        float v = acc[i][j][r];
        int c = colbase + j * 16;
        if (v > v1) { v2 = v1; c2 = c1_; v1 = v; c1_ = c; }
        else if (v > v2) { v2 = v; c2 = c; }
      }
#pragma unroll
      for (int msk = 1; msk < 16; msk <<= 1) {
        float u1 = __shfl_xor(v1, msk, 64);
        int   d1 = __shfl_xor(c1_, msk, 64);
        float u2 = __shfl_xor(v2, msk, 64);
        int   d2 = __shfl_xor(c2, msk, 64);
        merge2(v1, c1_, v2, c2, u1, d1, u2, d2);
      }
      if (lm == 0) {
        int rl = rm + i * 16 + lq * 4 + r;  // row within tile 0..127
        mv[rl][w & 1][0] = v1; mc[rl][w & 1][0] = c1_;
        mv[rl][w & 1][1] = v2; mc[rl][w & 1][1] = c2;
      }
    }
  }
  __syncthreads();
  if (tid < 128) {
    float v1 = mv[tid][0][0]; int c1_ = mc[tid][0][0];
    float v2 = mv[tid][0][1]; int c2 = mc[tid][0][1];
    merge2(v1, c1_, v2, c2, mv[tid][1][0], mc[tid][1][0], mv[tid][1][1], mc[tid][1][1]);
    size_t base = ((size_t)(m0 + tid) * NTILES + blockIdx.x) * 2;
    pv[base] = v1; pc[base] = c1_;
    pv[base + 1] = v2; pc[base + 1] = c2;
  }
}

// ---------------- exact fp64 refinement + winner select ----------------
__global__ __launch_bounds__(256) void select_kernel(
    const float* __restrict__ x, const float* __restrict__ kw,
    const float* __restrict__ pv, const int* __restrict__ pc,
    float* __restrict__ out_w, int* __restrict__ winners) {
  const int b = blockIdx.x;
  const int tid = threadIdx.x;
  __shared__ float sv[2 * NTILES];
  __shared__ int   sc[2 * NTILES];
  __shared__ double sredA[4], sredB[4];
  __shared__ double s_x2;
  __shared__ float s_M;
  __shared__ double s_best;
  __shared__ int s_bestc;

  if (tid < 2 * NTILES) {
    sv[tid] = pv[(size_t)b * 2 * NTILES + tid];
    sc[tid] = pc[(size_t)b * 2 * NTILES + tid];
  }

  // x2 in fp64 (float4 loads: 256 threads x 4 = 1024 = D)
  const float4* x4 = (const float4*)(x + (size_t)b * DD);
  float4 xv4 = x4[tid];
  double x2 = (double)xv4.x * xv4.x + (double)xv4.y * xv4.y +
              (double)xv4.z * xv4.z + (double)xv4.w * xv4.w;
#pragma unroll
  for (int o = 32; o >= 1; o >>= 1) x2 += __shfl_down(x2, o, 64);
  if ((tid & 63) == 0) sredA[tid >> 6] = x2;
  __syncthreads();
  if (tid == 0) {
    s_x2 = sredA[0] + sredA[1] + sredA[2] + sredA[3];
    float M = -1e30f;
    for (int e = 0; e < 2 * NTILES; ++e) M = fmaxf(M, sv[e]);
    s_M = M;
    s_best = 1e300;
    s_bestc = 0x7fffffff;
  }
  __syncthreads();

  const float thr = s_M - 0.01f;  // margin >> fp16-dot error (rms ~4e-4)
  for (int e = 0; e < 2 * NTILES; ++e) {
    if (sv[e] < thr) continue;  // block-uniform (LDS value)
    int col = sc[e];
    const float4* k4 = (const float4*)(kw + (size_t)col * DD);
    float4 wv4 = k4[tid];
    double dot = (double)xv4.x * wv4.x + (double)xv4.y * wv4.y +
                 (double)xv4.z * wv4.z + (double)xv4.w * wv4.w;
    double w2 = (double)wv4.x * wv4.x + (double)wv4.y * wv4.y +
                (double)wv4.z * wv4.z + (double)wv4.w * wv4.w;
#pragma unroll
    for (int o = 32; o >= 1; o >>= 1) {
      dot += __shfl_down(dot, o, 64);
      w2 += __shfl_down(w2, o, 64);
    }
    if ((tid & 63) == 0) { sredA[tid >> 6] = dot; sredB[tid >> 6] = w2; }
    __syncthreads();
    if (tid == 0) {
      double dsum = sredA[0] + sredA[1] + sredA[2] + sredA[3];
      double wsum = sredB[0] + sredB[1] + sredB[2] + sredB[3];
      double sq = s_x2 + wsum - 2.0 * dsum;
      if (sq < s_best || (sq == s_best && col < s_bestc)) {
        s_best = sq;
        s_bestc = col;
      }
    }
    __syncthreads();
  }
  if (tid == 0) {
    out_w[b] = (float)s_bestc;  // winners as fp32 (harness reads flat fp32)
    winners[b] = s_bestc;
  }
}

// ---------------- transpose G[O][H] -> Gt[H][O] ----------------
__global__ __launch_bounds__(256) void transpose_kernel(
    const float* __restrict__ G, float* __restrict__ Gt) {
  __shared__ float tile[32][33];
  const int h0 = blockIdx.x * 32;
  const int o0 = blockIdx.y * 32;
  const int tx = threadIdx.x & 31;
  const int ty = threadIdx.x >> 5;  // 0..7
#pragma unroll
  for (int j = 0; j < 4; ++j) {
    int o = o0 + ty + j * 8;
    if (o < OO) tile[ty + j * 8][tx] = G[(size_t)o * HH + h0 + tx];
  }
  __syncthreads();
#pragma unroll
  for (int j = 0; j < 4; ++j) {
    int o = o0 + tx;
    int h = h0 + ty + j * 8;
    if (o < OO) Gt[(size_t)h * OO + o] = tile[tx][ty + j * 8];
  }
}

// ---------------- gather (coalesced): out[b,:] = Gt[w_b,:] ----------------
__global__ __launch_bounds__(256) void gather_rows(
    const float* __restrict__ Gt, const int* __restrict__ winners,
    float* __restrict__ out) {
  const int b = blockIdx.x;
  const int q = threadIdx.x;        // float4 index, 250 per row
  if (q < OO / 4) {
    int w = winners[b];             // broadcast load
    ((float4*)out)[(size_t)b * (OO / 4) + q] =
        ((const float4*)(Gt + (size_t)w * OO))[q];
  }
}

// ---------------- fallback gather (no transpose) ----------------
__global__ __launch_bounds__(256) void gather_kernel(
    const float* __restrict__ G, const int* __restrict__ winners,
    float* __restrict__ out) {
  const int b = blockIdx.y;
  const int o = blockIdx.x * 256 + threadIdx.x;
  if (o < OO) {
    int w = winners[b];
    out[(size_t)b * OO + o] = G[(size_t)o * HH + w];
  }
}

extern "C" void kernel_launch(void* const* d_in, const int* in_sizes, int n_in,
                              void* d_out, int out_size, void* d_ws, size_t ws_size,
                              hipStream_t stream) {
  const float* x  = (const float*)d_in[0];  // [4096][1024]
  const float* kw = (const float*)d_in[1];  // [8192][1024]
  const float* gw = (const float*)d_in[2];  // [1000][8192]
  float* out = (float*)d_out;               // [4096*1000] output ++ [4096] winners

  // workspace layout
  const size_t MB = 1024 * 1024;
  char* ws = (char*)d_ws;
  f16*   xh      = (f16*)(ws);                 // 8 MB
  f16*   kh      = (f16*)(ws + 8 * MB);        // 16 MB
  float* pv      = (float*)(ws + 24 * MB);     // 2 MB
  int*   pc      = (int*)(ws + 26 * MB);       // 2 MB
  int*   winners = (int*)(ws + 28 * MB);       // 16 KB
  float* Gt      = (float*)(ws + 28 * MB + 65536);  // 32.77 MB
  const size_t need = 28 * MB + 65536 + sizeof(float) * (size_t)HH * OO;
  const bool use_transpose = ws_size >= need;

  // 1) fp32 -> fp16
  int cvt_blocks = (int)(((size_t)BB * DD / 4 + (size_t)HH * DD / 4 + 255) / 256);
  cvt_kernel<<<cvt_blocks, 256, 0, stream>>>(x, kw, xh, kh);

  // 2) fp16 MFMA GEMM + per-tile top-2
  dim3 g(HH / BN, BB / BM);  // (64, 32)
  gemm_top2<<<g, 256, 0, stream>>>(xh, kh, pv, pc);

  // 3) exact fp64 refinement -> winners
  select_kernel<<<BB, 256, 0, stream>>>(x, kw, pv, pc, out + (size_t)BB * OO, winners);

  // 4) gather output rows
  if (use_transpose) {
    transpose_kernel<<<dim3(HH / 32, (OO + 31) / 32), 256, 0, stream>>>(gw, Gt);
    gather_rows<<<BB, 256, 0, stream>>>(Gt, winners, out);
  } else {
    gather_kernel<<<dim3((OO + 255) / 256, BB), 256, 0, stream>>>(gw, winners, out);
  }
}

// Round 3
// 287.161 us; speedup vs baseline: 1.1033x; 1.0086x over previous
//
#include <hip/hip_runtime.h>
#include <hip/hip_bf16.h>
#include <hip/hip_fp16.h>

// Problem: B=4096, D=1024, H=8192, O=1000
//   winners[b] = argmin_h ||x_b - k_h||  (== argmax dot, k rows unit-norm)
//   output[b,o] = G[o, winners[b]]
// Pipeline (3 dispatches):
//   1) cvt: fp32->fp16 for x,kw + fp64 x2 per x-row
//   2) gemm_top2 (+fused G-transpose blocks): fp16 MFMA scores, per-(row,128-tile)
//      top-2 as packed 32-bit keys (monotone float bits | 7-bit col)
//   3) select (+fused gather): exact fp64 refinement of in-margin candidates,
//      then copy Gt[winner] row to output.

#define BB 4096
#define DD 1024
#define HH 8192
#define OO 1000

#define BM 128
#define BN 128
#define BK 32
#define NTILES (HH / BN)   // 64

typedef _Float16 f16;
typedef _Float16 f16x4 __attribute__((ext_vector_type(4)));
typedef _Float16 f16x8 __attribute__((ext_vector_type(8)));
typedef float f32x4 __attribute__((ext_vector_type(4)));

typedef __attribute__((address_space(3))) uint32_t lds_u32_t;
typedef __attribute__((address_space(1))) uint32_t glb_u32_t;

// ---- packed key: monotone(float) with low 7 bits = tile-local column ----
__device__ __forceinline__ uint32_t packkey(float v, int col) {
  uint32_t u = __float_as_uint(v);
  uint32_t mask = (uint32_t)((int32_t)u >> 31) | 0x80000000u;
  u ^= mask;                       // monotone: bigger float -> bigger uint
  return (u & 0xFFFFFF80u) | (uint32_t)col;
}
__device__ __forceinline__ float unpackval(uint32_t k) {
  uint32_t u = k & 0xFFFFFF80u;
  uint32_t mask = (k & 0x80000000u) ? 0x80000000u : 0xFFFFFFFFu;
  return __uint_as_float(u ^ mask);
}

// merge sorted pairs (k1>=k2),(o1>=o2) -> top-2 of the four
__device__ __forceinline__ void kmerge(uint32_t& k1, uint32_t& k2,
                                       uint32_t o1, uint32_t o2) {
  uint32_t mn = min(k1, o1);
  uint32_t alt = (k1 > o1) ? k2 : o2;
  k1 = max(k1, o1);
  k2 = max(mn, alt);
}

// ---------------- cvt: fp32->fp16 + per-row x2 (fp64) ----------------
// blocks 0..B-1: x row b (256 threads x float4 = 1024), reduce x2
// blocks B..B+H-1: kw row (convert only)
__global__ __launch_bounds__(256) void cvt_kernel(
    const float* __restrict__ x, const float* __restrict__ kw,
    f16* __restrict__ xh, f16* __restrict__ kh, double* __restrict__ x2g) {
  const int blk = blockIdx.x;
  const int tid = threadIdx.x;
  if (blk < BB) {
    float4 v = ((const float4*)(x + (size_t)blk * DD))[tid];
    f16x4 h;
    h[0] = (f16)v.x; h[1] = (f16)v.y; h[2] = (f16)v.z; h[3] = (f16)v.w;
    *(f16x4*)(xh + (size_t)blk * DD + 4 * tid) = h;
    double x2 = (double)v.x * v.x + (double)v.y * v.y +
                (double)v.z * v.z + (double)v.w * v.w;
#pragma unroll
    for (int o = 32; o >= 1; o >>= 1) x2 += __shfl_down(x2, o, 64);
    __shared__ double sred[4];
    if ((tid & 63) == 0) sred[tid >> 6] = x2;
    __syncthreads();
    if (tid == 0) x2g[blk] = sred[0] + sred[1] + sred[2] + sred[3];
  } else {
    int r = blk - BB;
    float4 v = ((const float4*)(kw + (size_t)r * DD))[tid];
    f16x4 h;
    h[0] = (f16)v.x; h[1] = (f16)v.y; h[2] = (f16)v.z; h[3] = (f16)v.w;
    *(f16x4*)(kh + (size_t)r * DD + 4 * tid) = h;
  }
}

// ---------------- GEMM (scores) + top-2 keys; fused G transpose ----------------
// blocks (bx, by<32): 128x128 C-tile of x @ kh^T; epilogue packs top-2 keys.
// blocks (bx, by in 32..35): 256 blocks x 32 (32x32) transpose tiles of G->Gt.
__global__ __launch_bounds__(256) void gemm_top2(
    const f16* __restrict__ A, const f16* __restrict__ Bt,
    uint2* __restrict__ pk,
    const float* __restrict__ G, float* __restrict__ Gt) {
  __shared__ __align__(16) f16 sA[BM * BK];  // 8 KB (also reused by transpose)
  __shared__ __align__(16) f16 sB[BN * BK];  // 8 KB
  __shared__ uint2 mk[128][2];               // 2 KB

  const int tid = threadIdx.x;

  if (blockIdx.y >= 32) {
    // -------- fused transpose: G[O][H] -> Gt[H][O] --------
    float (*tile)[33] = (float(*)[33])sA;  // 4224 B < 8 KB
    const int t = (blockIdx.y - 32) * 64 + blockIdx.x;  // 0..255
    const int tx = tid & 31;
    const int ty = tid >> 5;  // 0..7
    for (int tt = 0; tt < 32; ++tt) {
      int tile_id = t * 32 + tt;
      int h0 = (tile_id >> 5) * 32;   // 0..8160
      int o0 = (tile_id & 31) * 32;   // 0..992
      __syncthreads();
#pragma unroll
      for (int j = 0; j < 4; ++j) {
        int o = o0 + ty + j * 8;
        if (o < OO) tile[ty + j * 8][tx] = G[(size_t)o * HH + h0 + tx];
      }
      __syncthreads();
#pragma unroll
      for (int j = 0; j < 4; ++j) {
        int o = o0 + tx;
        int h = h0 + ty + j * 8;
        if (o < OO) Gt[(size_t)h * OO + o] = tile[tx][ty + j * 8];
      }
    }
    return;
  }

  const int w = tid >> 6;       // wave 0..3
  const int L = tid & 63;       // lane
  const int m0 = blockIdx.y * BM;
  const int n0 = blockIdx.x * BN;
  const int rm = (w >> 1) * 64;  // wave row base within tile
  const int cn = (w & 1) * 64;   // wave col base within tile

  f32x4 acc[4][4];
#pragma unroll
  for (int i = 0; i < 4; ++i)
#pragma unroll
    for (int j = 0; j < 4; ++j) {
      acc[i][j][0] = 0.f; acc[i][j][1] = 0.f; acc[i][j][2] = 0.f; acc[i][j][3] = 0.f;
    }

  const int lm = L & 15;    // fragment row within 16
  const int lq = L >> 4;    // quad -> k-offset lq*8

  // staging: thread owns chunks c0=tid, c1=tid+256 (chunk = 16B = 8 f16)
  // XOR-swizzled source so the lane-linear LDS write order stays intact.
  const int c0 = tid, c1 = tid + 256;
  const int r0 = c0 >> 2, r1 = c1 >> 2;
  const int s0 = ((c0 & 3) ^ (r0 & 3)) * 8;
  const int s1 = ((c1 & 3) ^ (r1 & 3)) * 8;
  const f16* pA0 = A + (size_t)(m0 + r0) * DD + s0;
  const f16* pA1 = A + (size_t)(m0 + r1) * DD + s1;
  const f16* pB0 = Bt + (size_t)(n0 + r0) * DD + s0;
  const f16* pB1 = Bt + (size_t)(n0 + r1) * DD + s1;

  const int ra = (rm + lm) * BK + ((lq ^ (lm & 3)) * 8);
  const int rb = (cn + lm) * BK + ((lq ^ (lm & 3)) * 8);

  for (int kt = 0; kt < DD / BK; ++kt) {
    __syncthreads();
    __builtin_amdgcn_global_load_lds((const glb_u32_t*)pA0, (lds_u32_t*)(sA + c0 * 8), 16, 0, 0);
    __builtin_amdgcn_global_load_lds((const glb_u32_t*)pA1, (lds_u32_t*)(sA + c1 * 8), 16, 0, 0);
    __builtin_amdgcn_global_load_lds((const glb_u32_t*)pB0, (lds_u32_t*)(sB + c0 * 8), 16, 0, 0);
    __builtin_amdgcn_global_load_lds((const glb_u32_t*)pB1, (lds_u32_t*)(sB + c1 * 8), 16, 0, 0);
    pA0 += BK; pA1 += BK; pB0 += BK; pB1 += BK;
    __syncthreads();

    f16x8 af[4], bf[4];
#pragma unroll
    for (int i = 0; i < 4; ++i)
      af[i] = *(const f16x8*)(sA + ra + i * 16 * BK);
#pragma unroll
    for (int j = 0; j < 4; ++j)
      bf[j] = *(const f16x8*)(sB + rb + j * 16 * BK);
#pragma unroll
    for (int i = 0; i < 4; ++i)
#pragma unroll
      for (int j = 0; j < 4; ++j)
        acc[i][j] = __builtin_amdgcn_mfma_f32_16x16x32_f16(af[i], bf[j], acc[i][j], 0, 0, 0);
  }

  // Epilogue: per-row top-2 over 128 cols, on packed 32-bit keys.
  // C/D layout (16x16x32): col = lane&15, row = (lane>>4)*4 + reg.
  const int col0 = cn + lm;  // tile-local column, 0..127 with +j*16
#pragma unroll
  for (int i = 0; i < 4; ++i) {
#pragma unroll
    for (int r = 0; r < 4; ++r) {
      uint32_t k1 = 0, k2 = 0;  // 0 < any real packed key
#pragma unroll
      for (int j = 0; j < 4; ++j) {
        uint32_t kj = packkey(acc[i][j][r], col0 + j * 16);
        if (kj > k1) { k2 = k1; k1 = kj; }
        else k2 = max(k2, kj);
      }
#pragma unroll
      for (int msk = 1; msk < 16; msk <<= 1) {
        uint32_t o1 = (uint32_t)__shfl_xor((int)k1, msk, 64);
        uint32_t o2 = (uint32_t)__shfl_xor((int)k2, msk, 64);
        kmerge(k1, k2, o1, o2);
      }
      if (lm == 0) {
        int rl = rm + i * 16 + lq * 4 + r;  // row within tile
        mk[rl][w & 1] = make_uint2(k1, k2);
      }
    }
  }
  __syncthreads();
  if (tid < 128) {
    uint2 a = mk[tid][0], b = mk[tid][1];
    kmerge(a.x, a.y, b.x, b.y);
    pk[(size_t)(m0 + tid) * NTILES + blockIdx.x] = a;
  }
}

// ---------------- select: exact fp64 refinement + fused gather ----------------
__global__ __launch_bounds__(256) void select_kernel(
    const float* __restrict__ x, const float* __restrict__ kw,
    const uint32_t* __restrict__ pk, const double* __restrict__ x2g,
    const float* __restrict__ Gt, float* __restrict__ out,
    float* __restrict__ out_w, int* __restrict__ winners) {
  const int b = blockIdx.x;
  const int tid = threadIdx.x;
  __shared__ uint32_t sk[128];
  __shared__ uint32_t s_mred[2];
  __shared__ uint32_t s_thrk;
  __shared__ double sredA[4], sredB[4];
  __shared__ double s_best;
  __shared__ int s_bestc;

  if (tid < 128) sk[tid] = pk[(size_t)b * 128 + tid];

  const float4* x4 = (const float4*)(x + (size_t)b * DD);
  float4 xv4 = x4[tid];
  __syncthreads();

  // parallel max over the 128 keys
  uint32_t m = (tid < 128) ? sk[tid] : 0;
#pragma unroll
  for (int msk = 1; msk < 64; msk <<= 1)
    m = max(m, (uint32_t)__shfl_xor((int)m, msk, 64));
  if ((tid & 63) == 0 && tid < 128) s_mred[tid >> 6] = m;
  __syncthreads();
  if (tid == 0) {
    uint32_t M = max(s_mred[0], s_mred[1]);
    float thr = unpackval(M) - 0.01f;  // margin >> fp16-dot error (rms ~4e-4)
    s_thrk = packkey(thr, 0);
    s_best = 1e300;
    s_bestc = 0x7fffffff;
  }
  __syncthreads();

  const uint32_t thrk = s_thrk;
  const double x2 = x2g[b];
  for (int e = 0; e < 128; ++e) {
    uint32_t ke = sk[e];          // block-uniform
    if (ke < thrk) continue;
    int col = (e >> 1) * 128 + (int)(ke & 127u);
    const float4* k4 = (const float4*)(kw + (size_t)col * DD);
    float4 wv4 = k4[tid];
    double dot = (double)xv4.x * wv4.x + (double)xv4.y * wv4.y +
                 (double)xv4.z * wv4.z + (double)xv4.w * wv4.w;
    double w2 = (double)wv4.x * wv4.x + (double)wv4.y * wv4.y +
                (double)wv4.z * wv4.z + (double)wv4.w * wv4.w;
#pragma unroll
    for (int o = 32; o >= 1; o >>= 1) {
      dot += __shfl_down(dot, o, 64);
      w2 += __shfl_down(w2, o, 64);
    }
    if ((tid & 63) == 0) { sredA[tid >> 6] = dot; sredB[tid >> 6] = w2; }
    __syncthreads();
    if (tid == 0) {
      double dsum = sredA[0] + sredA[1] + sredA[2] + sredA[3];
      double wsum = sredB[0] + sredB[1] + sredB[2] + sredB[3];
      double sq = x2 + wsum - 2.0 * dsum;
      if (sq < s_best || (sq == s_best && col < s_bestc)) {
        s_best = sq;
        s_bestc = col;
      }
    }
    __syncthreads();
  }

  const int wb = s_bestc;
  if (tid == 0) {
    out_w[b] = (float)wb;  // winners as fp32 (harness reads flat fp32)
    winners[b] = wb;
  }
  // fused gather: out[b,:] = Gt[wb,:]
  if (Gt != nullptr && tid < OO / 4) {
    ((float4*)out)[(size_t)b * (OO / 4) + tid] =
        ((const float4*)(Gt + (size_t)wb * OO))[tid];
  }
}

// ---------------- fallback gather (no transpose) ----------------
__global__ __launch_bounds__(256) void gather_kernel(
    const float* __restrict__ G, const int* __restrict__ winners,
    float* __restrict__ out) {
  const int b = blockIdx.y;
  const int o = blockIdx.x * 256 + threadIdx.x;
  if (o < OO) {
    int w = winners[b];
    out[(size_t)b * OO + o] = G[(size_t)o * HH + w];
  }
}

extern "C" void kernel_launch(void* const* d_in, const int* in_sizes, int n_in,
                              void* d_out, int out_size, void* d_ws, size_t ws_size,
                              hipStream_t stream) {
  const float* x  = (const float*)d_in[0];  // [4096][1024]
  const float* kw = (const float*)d_in[1];  // [8192][1024]
  const float* gw = (const float*)d_in[2];  // [1000][8192]
  float* out = (float*)d_out;               // [4096*1000] output ++ [4096] winners

  const size_t MB = 1024 * 1024;
  char* ws = (char*)d_ws;
  f16*    xh      = (f16*)(ws);                     // 8 MB
  f16*    kh      = (f16*)(ws + 8 * MB);            // 16 MB
  uint2*  pk      = (uint2*)(ws + 24 * MB);         // 2 MB
  double* x2g     = (double*)(ws + 26 * MB);        // 32 KB
  int*    winners = (int*)(ws + 26 * MB + 32768);   // 16 KB
  float*  Gt      = (float*)(ws + 26 * MB + 65536); // 32.77 MB
  const size_t need = 26 * MB + 65536 + sizeof(float) * (size_t)HH * OO;
  const bool use_transpose = ws_size >= need;

  // 1) fp32 -> fp16 (+ x2 per row)
  cvt_kernel<<<BB + HH, 256, 0, stream>>>(x, kw, xh, kh, x2g);

  // 2) fp16 MFMA GEMM + top-2 keys, with fused G transpose
  dim3 g(HH / BN, use_transpose ? 36 : 32);  // 2048 gemm (+256 transpose) blocks
  gemm_top2<<<g, 256, 0, stream>>>(xh, kh, pk, gw, use_transpose ? Gt : nullptr);

  // 3) exact fp64 refinement -> winners, fused coalesced gather
  select_kernel<<<BB, 256, 0, stream>>>(x, kw, (const uint32_t*)pk, x2g,
                                        use_transpose ? Gt : nullptr,
                                        out, out + (size_t)BB * OO, winners);

  // fallback gather if workspace too small for Gt
  if (!use_transpose) {
    gather_kernel<<<dim3((OO + 255) / 256, BB), 256, 0, stream>>>(gw, winners, out);
  }
}

// Round 4
// 282.654 us; speedup vs baseline: 1.1209x; 1.0159x over previous
//
#include <hip/hip_runtime.h>
#include <hip/hip_bf16.h>
#include <hip/hip_fp16.h>

// Problem: B=4096, D=1024, H=8192, O=1000
//   winners[b] = argmin_h ||x_b - k_h||  (== argmax dot, k rows unit-norm)
//   output[b,o] = G[o, winners[b]]
// Pipeline (3 dispatches):
//   1) cvt (+fused G-transpose): fp32->fp16 for x,kw; fp64 x2 per x-row; G->Gt
//   2) gemm_top2: fp16 MFMA scores (BK=64: 16 iters, 32 MFMA/iter, XOR-swizzled
//      LDS), per-(row,128-col-tile) top-2 as packed 32-bit keys
//   3) select (+fused gather): exact fp64 refinement of in-margin candidates,
//      then copy Gt[winner] row to output.

#define BB 4096
#define DD 1024
#define HH 8192
#define OO 1000

#define BM 128
#define BN 128
#define BK 64
#define NTILES (HH / BN)   // 64

typedef _Float16 f16;
typedef _Float16 f16x4 __attribute__((ext_vector_type(4)));
typedef _Float16 f16x8 __attribute__((ext_vector_type(8)));
typedef float f32x4 __attribute__((ext_vector_type(4)));

typedef __attribute__((address_space(3))) uint32_t lds_u32_t;
typedef __attribute__((address_space(1))) uint32_t glb_u32_t;

// ---- packed key: monotone(float) with low 7 bits = tile-local column ----
__device__ __forceinline__ uint32_t packkey(float v, int col) {
  uint32_t u = __float_as_uint(v);
  uint32_t mask = (uint32_t)((int32_t)u >> 31) | 0x80000000u;
  u ^= mask;                       // monotone: bigger float -> bigger uint
  return (u & 0xFFFFFF80u) | (uint32_t)col;
}
__device__ __forceinline__ float unpackval(uint32_t k) {
  uint32_t u = k & 0xFFFFFF80u;
  uint32_t mask = (k & 0x80000000u) ? 0x80000000u : 0xFFFFFFFFu;
  return __uint_as_float(u ^ mask);
}

// merge sorted pairs (k1>=k2),(o1>=o2) -> top-2 of the four
__device__ __forceinline__ void kmerge(uint32_t& k1, uint32_t& k2,
                                       uint32_t o1, uint32_t o2) {
  uint32_t mn = min(k1, o1);
  uint32_t alt = (k1 > o1) ? k2 : o2;
  k1 = max(k1, o1);
  k2 = max(mn, alt);
}

// ---------------- cvt: fp32->fp16 + per-row x2 (fp64) + fused transpose ------
// blocks [0,B): x row (256 threads x float4 = 1024), convert + reduce x2
// blocks [B, B+H): kw row (convert only)
// blocks [B+H, B+H+256): G[O][H] -> Gt[H][O] transpose, 32 (32x32)-tiles each
__global__ __launch_bounds__(256) void cvt_kernel(
    const float* __restrict__ x, const float* __restrict__ kw,
    f16* __restrict__ xh, f16* __restrict__ kh, double* __restrict__ x2g,
    const float* __restrict__ G, float* __restrict__ Gt) {
  const int blk = blockIdx.x;
  const int tid = threadIdx.x;
  __shared__ float tile[32][33];  // 4224 B (also covers sred)
  if (blk < BB) {
    float4 v = ((const float4*)(x + (size_t)blk * DD))[tid];
    f16x4 h;
    h[0] = (f16)v.x; h[1] = (f16)v.y; h[2] = (f16)v.z; h[3] = (f16)v.w;
    *(f16x4*)(xh + (size_t)blk * DD + 4 * tid) = h;
    double x2 = (double)v.x * v.x + (double)v.y * v.y +
                (double)v.z * v.z + (double)v.w * v.w;
#pragma unroll
    for (int o = 32; o >= 1; o >>= 1) x2 += __shfl_down(x2, o, 64);
    double* sred = (double*)tile;
    if ((tid & 63) == 0) sred[tid >> 6] = x2;
    __syncthreads();
    if (tid == 0) x2g[blk] = sred[0] + sred[1] + sred[2] + sred[3];
  } else if (blk < BB + HH) {
    int r = blk - BB;
    float4 v = ((const float4*)(kw + (size_t)r * DD))[tid];
    f16x4 h;
    h[0] = (f16)v.x; h[1] = (f16)v.y; h[2] = (f16)v.z; h[3] = (f16)v.w;
    *(f16x4*)(kh + (size_t)r * DD + 4 * tid) = h;
  } else {
    const int t = blk - (BB + HH);  // 0..255
    const int tx = tid & 31;
    const int ty = tid >> 5;  // 0..7
    for (int tt = 0; tt < 32; ++tt) {
      int tile_id = t * 32 + tt;       // 0..8191
      int h0 = (tile_id >> 5) * 32;    // 0..8160
      int o0 = (tile_id & 31) * 32;    // 0..992
      __syncthreads();
#pragma unroll
      for (int j = 0; j < 4; ++j) {
        int o = o0 + ty + j * 8;
        if (o < OO) tile[ty + j * 8][tx] = G[(size_t)o * HH + h0 + tx];
      }
      __syncthreads();
#pragma unroll
      for (int j = 0; j < 4; ++j) {
        int o = o0 + tx;
        int h = h0 + ty + j * 8;
        if (o < OO) Gt[(size_t)h * OO + o] = tile[tx][ty + j * 8];
      }
    }
  }
}

// ---------------- GEMM (scores) + top-2 keys ----------------
// A = xh [B][D] fp16, Bt = kh [H][D] fp16 (NT layout). Block: 128x128 C-tile,
// BK=64 (16 K-iters, 32 MFMA + 16 ds_read_b128 per iter).
// LDS XOR swizzle per 16B chunk (8 chunks/row): LDS chunk (row, c) holds
// source chunk (row, c ^ (row&7)). Writer (global_load_lds) stays lane-linear
// in LDS and permutes its SOURCE address; reader lanes spread 2/bank (free).
__global__ __launch_bounds__(256) void gemm_top2(
    const f16* __restrict__ A, const f16* __restrict__ Bt,
    uint2* __restrict__ pk) {
  __shared__ __align__(16) f16 sA[BM * BK];  // 16 KB
  __shared__ __align__(16) f16 sB[BN * BK];  // 16 KB
  __shared__ uint2 mk[128][2];               // 2 KB

  const int tid = threadIdx.x;
  const int w = tid >> 6;       // wave 0..3
  const int L = tid & 63;       // lane
  const int m0 = blockIdx.y * BM;
  const int n0 = blockIdx.x * BN;
  const int rm = (w >> 1) * 64;  // wave row base within tile
  const int cn = (w & 1) * 64;   // wave col base within tile

  f32x4 acc[4][4];
#pragma unroll
  for (int i = 0; i < 4; ++i)
#pragma unroll
    for (int j = 0; j < 4; ++j) {
      acc[i][j][0] = 0.f; acc[i][j][1] = 0.f; acc[i][j][2] = 0.f; acc[i][j][3] = 0.f;
    }

  const int lm = L & 15;    // fragment row within 16
  const int lq = L >> 4;    // quad -> k-offset lq*8

  // staging: thread owns LDS chunks tid + j*256, j=0..3 (chunk = 16B = 8 f16)
  // chunk c: row = c>>3 (0..127), lds-chunk-in-row = c&7,
  // source chunk = (c&7) ^ (row&7); rows for j differ by 32 -> row&7 invariant.
  const int r0 = tid >> 3;
  const int sc0 = ((tid & 7) ^ (r0 & 7)) * 8;  // source k-offset (f16)
  const f16* pA = A + (size_t)(m0 + r0) * DD + sc0;
  const f16* pB = Bt + (size_t)(n0 + r0) * DD + sc0;
  const size_t rstep = (size_t)32 * DD;  // +32 rows per j

  // fragment read base: row*BK + ((khalf*4+lq) ^ (row&7))*8 ; row&7 == lm&7
  const int swz = (lm & 7);
  const int ra0 = (rm + lm) * BK + ((0 * 4 + lq) ^ swz) * 8;
  const int ra1 = (rm + lm) * BK + ((1 * 4 + lq) ^ swz) * 8;
  const int rb0 = (cn + lm) * BK + ((0 * 4 + lq) ^ swz) * 8;
  const int rb1 = (cn + lm) * BK + ((1 * 4 + lq) ^ swz) * 8;

  for (int kt = 0; kt < DD / BK; ++kt) {
    __syncthreads();  // prev compute done before overwriting LDS
#pragma unroll
    for (int j = 0; j < 4; ++j) {
      __builtin_amdgcn_global_load_lds((const glb_u32_t*)(pA + j * rstep),
                                       (lds_u32_t*)(sA + (tid + j * 256) * 8), 16, 0, 0);
      __builtin_amdgcn_global_load_lds((const glb_u32_t*)(pB + j * rstep),
                                       (lds_u32_t*)(sB + (tid + j * 256) * 8), 16, 0, 0);
    }
    pA += BK; pB += BK;
    __syncthreads();  // drains vmcnt before use

    f16x8 af[4], bf[4];
    // k-half 0
#pragma unroll
    for (int i = 0; i < 4; ++i)
      af[i] = *(const f16x8*)(sA + ra0 + i * 16 * BK);
#pragma unroll
    for (int j = 0; j < 4; ++j)
      bf[j] = *(const f16x8*)(sB + rb0 + j * 16 * BK);
#pragma unroll
    for (int i = 0; i < 4; ++i)
#pragma unroll
      for (int j = 0; j < 4; ++j)
        acc[i][j] = __builtin_amdgcn_mfma_f32_16x16x32_f16(af[i], bf[j], acc[i][j], 0, 0, 0);
    // k-half 1
#pragma unroll
    for (int i = 0; i < 4; ++i)
      af[i] = *(const f16x8*)(sA + ra1 + i * 16 * BK);
#pragma unroll
    for (int j = 0; j < 4; ++j)
      bf[j] = *(const f16x8*)(sB + rb1 + j * 16 * BK);
#pragma unroll
    for (int i = 0; i < 4; ++i)
#pragma unroll
      for (int j = 0; j < 4; ++j)
        acc[i][j] = __builtin_amdgcn_mfma_f32_16x16x32_f16(af[i], bf[j], acc[i][j], 0, 0, 0);
  }

  // Epilogue: per-row top-2 over 128 cols, on packed 32-bit keys.
  // C/D layout (16x16x32): col = lane&15, row = (lane>>4)*4 + reg.
  const int col0 = cn + lm;  // tile-local column, 0..127 with +j*16
#pragma unroll
  for (int i = 0; i < 4; ++i) {
#pragma unroll
    for (int r = 0; r < 4; ++r) {
      uint32_t k1 = 0, k2 = 0;  // 0 < any real packed key
#pragma unroll
      for (int j = 0; j < 4; ++j) {
        uint32_t kj = packkey(acc[i][j][r], col0 + j * 16);
        if (kj > k1) { k2 = k1; k1 = kj; }
        else k2 = max(k2, kj);
      }
#pragma unroll
      for (int msk = 1; msk < 16; msk <<= 1) {
        uint32_t o1 = (uint32_t)__shfl_xor((int)k1, msk, 64);
        uint32_t o2 = (uint32_t)__shfl_xor((int)k2, msk, 64);
        kmerge(k1, k2, o1, o2);
      }
      if (lm == 0) {
        int rl = rm + i * 16 + lq * 4 + r;  // row within tile
        mk[rl][w & 1] = make_uint2(k1, k2);
      }
    }
  }
  __syncthreads();
  if (tid < 128) {
    uint2 a = mk[tid][0], b = mk[tid][1];
    kmerge(a.x, a.y, b.x, b.y);
    pk[(size_t)(m0 + tid) * NTILES + blockIdx.x] = a;
  }
}

// ---------------- select: exact fp64 refinement + fused gather ----------------
__global__ __launch_bounds__(256) void select_kernel(
    const float* __restrict__ x, const float* __restrict__ kw,
    const uint32_t* __restrict__ pk, const double* __restrict__ x2g,
    const float* __restrict__ Gt, float* __restrict__ out,
    float* __restrict__ out_w, int* __restrict__ winners) {
  const int b = blockIdx.x;
  const int tid = threadIdx.x;
  __shared__ uint32_t sk[128];
  __shared__ uint32_t s_mred[2];
  __shared__ uint32_t s_thrk;
  __shared__ double sredA[4], sredB[4];
  __shared__ double s_best;
  __shared__ int s_bestc;

  if (tid < 128) sk[tid] = pk[(size_t)b * 128 + tid];

  const float4* x4 = (const float4*)(x + (size_t)b * DD);
  float4 xv4 = x4[tid];
  __syncthreads();

  // parallel max over the 128 keys
  uint32_t m = (tid < 128) ? sk[tid] : 0;
#pragma unroll
  for (int msk = 1; msk < 64; msk <<= 1)
    m = max(m, (uint32_t)__shfl_xor((int)m, msk, 64));
  if ((tid & 63) == 0 && tid < 128) s_mred[tid >> 6] = m;
  __syncthreads();
  if (tid == 0) {
    uint32_t M = max(s_mred[0], s_mred[1]);
    float thr = unpackval(M) - 0.01f;  // margin >> fp16-dot error (rms ~4e-4)
    s_thrk = packkey(thr, 0);
    s_best = 1e300;
    s_bestc = 0x7fffffff;
  }
  __syncthreads();

  const uint32_t thrk = s_thrk;
  const double x2 = x2g[b];
  for (int e = 0; e < 128; ++e) {
    uint32_t ke = sk[e];          // block-uniform
    if (ke < thrk) continue;
    int col = (e >> 1) * 128 + (int)(ke & 127u);
    const float4* k4 = (const float4*)(kw + (size_t)col * DD);
    float4 wv4 = k4[tid];
    double dot = (double)xv4.x * wv4.x + (double)xv4.y * wv4.y +
                 (double)xv4.z * wv4.z + (double)xv4.w * wv4.w;
    double w2 = (double)wv4.x * wv4.x + (double)wv4.y * wv4.y +
                (double)wv4.z * wv4.z + (double)wv4.w * wv4.w;
#pragma unroll
    for (int o = 32; o >= 1; o >>= 1) {
      dot += __shfl_down(dot, o, 64);
      w2 += __shfl_down(w2, o, 64);
    }
    if ((tid & 63) == 0) { sredA[tid >> 6] = dot; sredB[tid >> 6] = w2; }
    __syncthreads();
    if (tid == 0) {
      double dsum = sredA[0] + sredA[1] + sredA[2] + sredA[3];
      double wsum = sredB[0] + sredB[1] + sredB[2] + sredB[3];
      double sq = x2 + wsum - 2.0 * dsum;
      if (sq < s_best || (sq == s_best && col < s_bestc)) {
        s_best = sq;
        s_bestc = col;
      }
    }
    __syncthreads();
  }

  const int wb = s_bestc;
  if (tid == 0) {
    out_w[b] = (float)wb;  // winners as fp32 (harness reads flat fp32)
    winners[b] = wb;
  }
  // fused gather: out[b,:] = Gt[wb,:]
  if (Gt != nullptr && tid < OO / 4) {
    ((float4*)out)[(size_t)b * (OO / 4) + tid] =
        ((const float4*)(Gt + (size_t)wb * OO))[tid];
  }
}

// ---------------- fallback gather (no transpose) ----------------
__global__ __launch_bounds__(256) void gather_kernel(
    const float* __restrict__ G, const int* __restrict__ winners,
    float* __restrict__ out) {
  const int b = blockIdx.y;
  const int o = blockIdx.x * 256 + threadIdx.x;
  if (o < OO) {
    int w = winners[b];
    out[(size_t)b * OO + o] = G[(size_t)o * HH + w];
  }
}

extern "C" void kernel_launch(void* const* d_in, const int* in_sizes, int n_in,
                              void* d_out, int out_size, void* d_ws, size_t ws_size,
                              hipStream_t stream) {
  const float* x  = (const float*)d_in[0];  // [4096][1024]
  const float* kw = (const float*)d_in[1];  // [8192][1024]
  const float* gw = (const float*)d_in[2];  // [1000][8192]
  float* out = (float*)d_out;               // [4096*1000] output ++ [4096] winners

  const size_t MB = 1024 * 1024;
  char* ws = (char*)d_ws;
  f16*    xh      = (f16*)(ws);                     // 8 MB
  f16*    kh      = (f16*)(ws + 8 * MB);            // 16 MB
  uint2*  pk      = (uint2*)(ws + 24 * MB);         // 2 MB
  double* x2g     = (double*)(ws + 26 * MB);        // 32 KB
  int*    winners = (int*)(ws + 26 * MB + 32768);   // 16 KB
  float*  Gt      = (float*)(ws + 26 * MB + 65536); // 32.77 MB
  const size_t need = 26 * MB + 65536 + sizeof(float) * (size_t)HH * OO;
  const bool use_transpose = ws_size >= need;

  // 1) fp32 -> fp16 (+ x2 per row, + fused G transpose)
  int cvt_blocks = BB + HH + (use_transpose ? 256 : 0);
  cvt_kernel<<<cvt_blocks, 256, 0, stream>>>(x, kw, xh, kh, x2g, gw,
                                             use_transpose ? Gt : nullptr);

  // 2) fp16 MFMA GEMM + top-2 keys
  dim3 g(HH / BN, BB / BM);  // (64, 32)
  gemm_top2<<<g, 256, 0, stream>>>(xh, kh, pk);

  // 3) exact fp64 refinement -> winners, fused coalesced gather
  select_kernel<<<BB, 256, 0, stream>>>(x, kw, (const uint32_t*)pk, x2g,
                                        use_transpose ? Gt : nullptr,
                                        out, out + (size_t)BB * OO, winners);

  // fallback gather if workspace too small for Gt
  if (!use_transpose) {
    gather_kernel<<<dim3((OO + 255) / 256, BB), 256, 0, stream>>>(gw, winners, out);
  }
}

// Round 5
// 225.958 us; speedup vs baseline: 1.4021x; 1.2509x over previous
//
#include <hip/hip_runtime.h>
#include <hip/hip_bf16.h>
#include <hip/hip_fp16.h>

// Problem: B=4096, D=1024, H=8192, O=1000
//   winners[b] = argmin_h ||x_b - k_h||  (== argmax dot, k rows unit-norm)
//   output[b,o] = G[o, winners[b]]
// Pipeline (3 dispatches):
//   1) cvt: fp32->fp16 for x,kw  + fully-parallel G->Gt transpose tiles
//   2) gemm_top2: fp16 MFMA scores (BK=64, XOR-swizzled LDS), per-(row,128-tile)
//      top-2 as packed 32-bit keys
//   3) select: wave-per-row exact fp64 refinement (no barriers) + fused gather.

#define BB 4096
#define DD 1024
#define HH 8192
#define OO 1000

#define BM 128
#define BN 128
#define BK 64
#define NTILES (HH / BN)   // 64

typedef _Float16 f16;
typedef _Float16 f16x4 __attribute__((ext_vector_type(4)));
typedef _Float16 f16x8 __attribute__((ext_vector_type(8)));
typedef float f32x4 __attribute__((ext_vector_type(4)));

typedef __attribute__((address_space(3))) uint32_t lds_u32_t;
typedef __attribute__((address_space(1))) uint32_t glb_u32_t;

// ---- packed key: monotone(float) with low 7 bits = tile-local column ----
__device__ __forceinline__ uint32_t packkey(float v, int col) {
  uint32_t u = __float_as_uint(v);
  uint32_t mask = (uint32_t)((int32_t)u >> 31) | 0x80000000u;
  u ^= mask;                       // monotone: bigger float -> bigger uint
  return (u & 0xFFFFFF80u) | (uint32_t)col;
}
__device__ __forceinline__ float unpackval(uint32_t k) {
  uint32_t u = k & 0xFFFFFF80u;
  uint32_t mask = (k & 0x80000000u) ? 0x80000000u : 0xFFFFFFFFu;
  return __uint_as_float(u ^ mask);
}

// merge sorted pairs (k1>=k2),(o1>=o2) -> top-2 of the four
__device__ __forceinline__ void kmerge(uint32_t& k1, uint32_t& k2,
                                       uint32_t o1, uint32_t o2) {
  uint32_t mn = min(k1, o1);
  uint32_t alt = (k1 > o1) ? k2 : o2;
  k1 = max(k1, o1);
  k2 = max(mn, alt);
}

// ---------------- cvt: fp32->fp16 + fully-parallel G transpose --------------
// blocks [0,B): x row (256 threads x float4 = 1024), convert
// blocks [B, B+H): kw row (convert only)
// blocks [B+H, B+H+8192): one 32x32 transpose tile of G[O][H] -> Gt[H][O]
__global__ __launch_bounds__(256) void cvt_kernel(
    const float* __restrict__ x, const float* __restrict__ kw,
    f16* __restrict__ xh, f16* __restrict__ kh,
    const float* __restrict__ G, float* __restrict__ Gt) {
  const int blk = blockIdx.x;
  const int tid = threadIdx.x;
  __shared__ float tile[32][33];
  if (blk < BB + HH) {
    const float* src = (blk < BB) ? (x + (size_t)blk * DD)
                                  : (kw + (size_t)(blk - BB) * DD);
    f16* dst = (blk < BB) ? (xh + (size_t)blk * DD)
                          : (kh + (size_t)(blk - BB) * DD);
    float4 v = ((const float4*)src)[tid];
    f16x4 h;
    h[0] = (f16)v.x; h[1] = (f16)v.y; h[2] = (f16)v.z; h[3] = (f16)v.w;
    *(f16x4*)(dst + 4 * tid) = h;
  } else {
    const int tile_id = blk - (BB + HH);   // 0..8191
    const int h0 = (tile_id >> 5) * 32;    // 0..8160
    const int o0 = (tile_id & 31) * 32;    // 0..992
    const int tx = tid & 31;
    const int ty = tid >> 5;  // 0..7
#pragma unroll
    for (int j = 0; j < 4; ++j) {
      int o = o0 + ty + j * 8;
      if (o < OO) tile[ty + j * 8][tx] = G[(size_t)o * HH + h0 + tx];
    }
    __syncthreads();
#pragma unroll
    for (int j = 0; j < 4; ++j) {
      int o = o0 + tx;
      int h = h0 + ty + j * 8;
      if (o < OO) Gt[(size_t)h * OO + o] = tile[tx][ty + j * 8];
    }
  }
}

// ---------------- GEMM (scores) + top-2 keys ----------------
// A = xh [B][D] fp16, Bt = kh [H][D] fp16 (NT layout). Block: 128x128 C-tile,
// BK=64 (16 K-iters, 32 MFMA + 16 ds_read_b128 per iter).
// LDS XOR swizzle per 16B chunk (8 chunks/row): LDS chunk (row, c) holds
// source chunk (row, c ^ (row&7)). Writer (global_load_lds) stays lane-linear
// in LDS and permutes its SOURCE address; reader lanes spread 2/bank (free).
__global__ __launch_bounds__(256) void gemm_top2(
    const f16* __restrict__ A, const f16* __restrict__ Bt,
    uint2* __restrict__ pk) {
  __shared__ __align__(16) f16 sA[BM * BK];  // 16 KB
  __shared__ __align__(16) f16 sB[BN * BK];  // 16 KB
  __shared__ uint2 mk[128][2];               // 2 KB

  const int tid = threadIdx.x;
  const int w = tid >> 6;       // wave 0..3
  const int L = tid & 63;       // lane
  const int m0 = blockIdx.y * BM;
  const int n0 = blockIdx.x * BN;
  const int rm = (w >> 1) * 64;  // wave row base within tile
  const int cn = (w & 1) * 64;   // wave col base within tile

  f32x4 acc[4][4];
#pragma unroll
  for (int i = 0; i < 4; ++i)
#pragma unroll
    for (int j = 0; j < 4; ++j) {
      acc[i][j][0] = 0.f; acc[i][j][1] = 0.f; acc[i][j][2] = 0.f; acc[i][j][3] = 0.f;
    }

  const int lm = L & 15;    // fragment row within 16
  const int lq = L >> 4;    // quad -> k-offset lq*8

  // staging: thread owns LDS chunks tid + j*256, j=0..3 (chunk = 16B = 8 f16)
  const int r0 = tid >> 3;
  const int sc0 = ((tid & 7) ^ (r0 & 7)) * 8;  // swizzled source k-offset (f16)
  const f16* pA = A + (size_t)(m0 + r0) * DD + sc0;
  const f16* pB = Bt + (size_t)(n0 + r0) * DD + sc0;
  const size_t rstep = (size_t)32 * DD;  // +32 rows per j

  // fragment read base: row*BK + ((khalf*4+lq) ^ (row&7))*8 ; row&7 == lm&7
  const int swz = (lm & 7);
  const int ra0 = (rm + lm) * BK + ((0 * 4 + lq) ^ swz) * 8;
  const int ra1 = (rm + lm) * BK + ((1 * 4 + lq) ^ swz) * 8;
  const int rb0 = (cn + lm) * BK + ((0 * 4 + lq) ^ swz) * 8;
  const int rb1 = (cn + lm) * BK + ((1 * 4 + lq) ^ swz) * 8;

  for (int kt = 0; kt < DD / BK; ++kt) {
    __syncthreads();  // prev compute done before overwriting LDS
#pragma unroll
    for (int j = 0; j < 4; ++j) {
      __builtin_amdgcn_global_load_lds((const glb_u32_t*)(pA + j * rstep),
                                       (lds_u32_t*)(sA + (tid + j * 256) * 8), 16, 0, 0);
      __builtin_amdgcn_global_load_lds((const glb_u32_t*)(pB + j * rstep),
                                       (lds_u32_t*)(sB + (tid + j * 256) * 8), 16, 0, 0);
    }
    pA += BK; pB += BK;
    __syncthreads();  // drains vmcnt before use

    f16x8 af[4], bf[4];
    // k-half 0
#pragma unroll
    for (int i = 0; i < 4; ++i)
      af[i] = *(const f16x8*)(sA + ra0 + i * 16 * BK);
#pragma unroll
    for (int j = 0; j < 4; ++j)
      bf[j] = *(const f16x8*)(sB + rb0 + j * 16 * BK);
#pragma unroll
    for (int i = 0; i < 4; ++i)
#pragma unroll
      for (int j = 0; j < 4; ++j)
        acc[i][j] = __builtin_amdgcn_mfma_f32_16x16x32_f16(af[i], bf[j], acc[i][j], 0, 0, 0);
    // k-half 1
#pragma unroll
    for (int i = 0; i < 4; ++i)
      af[i] = *(const f16x8*)(sA + ra1 + i * 16 * BK);
#pragma unroll
    for (int j = 0; j < 4; ++j)
      bf[j] = *(const f16x8*)(sB + rb1 + j * 16 * BK);
#pragma unroll
    for (int i = 0; i < 4; ++i)
#pragma unroll
      for (int j = 0; j < 4; ++j)
        acc[i][j] = __builtin_amdgcn_mfma_f32_16x16x32_f16(af[i], bf[j], acc[i][j], 0, 0, 0);
  }

  // Epilogue: per-row top-2 over 128 cols, on packed 32-bit keys.
  // C/D layout (16x16x32): col = lane&15, row = (lane>>4)*4 + reg.
  const int col0 = cn + lm;  // tile-local column, 0..127 with +j*16
#pragma unroll
  for (int i = 0; i < 4; ++i) {
#pragma unroll
    for (int r = 0; r < 4; ++r) {
      uint32_t k1 = 0, k2 = 0;  // 0 < any real packed key
#pragma unroll
      for (int j = 0; j < 4; ++j) {
        uint32_t kj = packkey(acc[i][j][r], col0 + j * 16);
        if (kj > k1) { k2 = k1; k1 = kj; }
        else k2 = max(k2, kj);
      }
#pragma unroll
      for (int msk = 1; msk < 16; msk <<= 1) {
        uint32_t o1 = (uint32_t)__shfl_xor((int)k1, msk, 64);
        uint32_t o2 = (uint32_t)__shfl_xor((int)k2, msk, 64);
        kmerge(k1, k2, o1, o2);
      }
      if (lm == 0) {
        int rl = rm + i * 16 + lq * 4 + r;  // row within tile
        mk[rl][w & 1] = make_uint2(k1, k2);
      }
    }
  }
  __syncthreads();
  if (tid < 128) {
    uint2 a = mk[tid][0], b = mk[tid][1];
    kmerge(a.x, a.y, b.x, b.y);
    pk[(size_t)(m0 + tid) * NTILES + blockIdx.x] = a;
  }
}

// ------- select: wave-per-row exact fp64 refinement + fused gather ----------
// One 64-lane wave per x-row; 4 rows per 256-thread block. No __syncthreads.
__global__ __launch_bounds__(256) void select_kernel(
    const float* __restrict__ x, const float* __restrict__ kw,
    const uint2* __restrict__ pk,
    const float* __restrict__ Gt, float* __restrict__ out,
    float* __restrict__ out_w, int* __restrict__ winners) {
  const int b = blockIdx.x * 4 + (threadIdx.x >> 6);
  const int L = threadIdx.x & 63;

  // x row: 16 floats/lane (4 x float4, coalesced)
  const float4* x4 = (const float4*)(x + (size_t)b * DD);
  float4 xv[4];
#pragma unroll
  for (int j = 0; j < 4; ++j) xv[j] = x4[L + 64 * j];

  // keys of tile L (top-2, packed, k1>=k2)
  uint2 kp = pk[(size_t)b * NTILES + L];

  // x2 in fp64 (xor-reduce -> all lanes hold total)
  double x2 = 0.0;
#pragma unroll
  for (int j = 0; j < 4; ++j)
    x2 += (double)xv[j].x * xv[j].x + (double)xv[j].y * xv[j].y +
          (double)xv[j].z * xv[j].z + (double)xv[j].w * xv[j].w;
#pragma unroll
  for (int msk = 1; msk < 64; msk <<= 1) x2 += __shfl_xor(x2, msk, 64);

  // global max key -> margin threshold
  uint32_t m = kp.x;
#pragma unroll
  for (int msk = 1; msk < 64; msk <<= 1)
    m = max(m, (uint32_t)__shfl_xor((int)m, msk, 64));
  const uint32_t thrk = packkey(unpackval(m) - 0.01f, 0);  // margin >> fp16 err

  unsigned long long cand1 = __ballot(kp.x >= thrk);
  unsigned long long cand2 = __ballot(kp.y >= thrk);

  double best = 1e300;
  int bestc = 0x7fffffff;
#pragma unroll 1
  for (int pass = 0; pass < 2; ++pass) {
    unsigned long long bits = (pass == 0) ? cand1 : cand2;
    uint32_t mykey = (pass == 0) ? kp.x : kp.y;
    while (bits) {
      int t = __ffsll((long long)bits) - 1;   // candidate's tile = lane t
      bits &= bits - 1;
      uint32_t kbt = (uint32_t)__shfl((int)mykey, t, 64);
      int col = t * 128 + (int)(kbt & 127u);
      const float4* k4 = (const float4*)(kw + (size_t)col * DD);
      double dot = 0.0, w2 = 0.0;
#pragma unroll
      for (int j = 0; j < 4; ++j) {
        float4 wv = k4[L + 64 * j];
        dot += (double)xv[j].x * wv.x + (double)xv[j].y * wv.y +
               (double)xv[j].z * wv.z + (double)xv[j].w * wv.w;
        w2 += (double)wv.x * wv.x + (double)wv.y * wv.y +
              (double)wv.z * wv.z + (double)wv.w * wv.w;
      }
#pragma unroll
      for (int msk = 1; msk < 64; msk <<= 1) {
        dot += __shfl_xor(dot, msk, 64);
        w2 += __shfl_xor(w2, msk, 64);
      }
      double sq = x2 + w2 - 2.0 * dot;   // identical on all lanes
      if (sq < best || (sq == best && col < bestc)) { best = sq; bestc = col; }
    }
  }

  if (L == 0) {
    out_w[b] = (float)bestc;  // winners as fp32 (harness reads flat fp32)
    winners[b] = bestc;
  }
  // fused gather: out[b,:] = Gt[bestc,:]  (wave-uniform bestc)
  if (Gt != nullptr) {
    const float4* gsrc = (const float4*)(Gt + (size_t)bestc * OO);
    float4* gdst = (float4*)(out + (size_t)b * OO);
#pragma unroll
    for (int j = 0; j < 4; ++j) {
      int q = L + 64 * j;
      if (q < OO / 4) gdst[q] = gsrc[q];
    }
  }
}

// ---------------- fallback gather (no transpose) ----------------
__global__ __launch_bounds__(256) void gather_kernel(
    const float* __restrict__ G, const int* __restrict__ winners,
    float* __restrict__ out) {
  const int b = blockIdx.y;
  const int o = blockIdx.x * 256 + threadIdx.x;
  if (o < OO) {
    int w = winners[b];
    out[(size_t)b * OO + o] = G[(size_t)o * HH + w];
  }
}

extern "C" void kernel_launch(void* const* d_in, const int* in_sizes, int n_in,
                              void* d_out, int out_size, void* d_ws, size_t ws_size,
                              hipStream_t stream) {
  const float* x  = (const float*)d_in[0];  // [4096][1024]
  const float* kw = (const float*)d_in[1];  // [8192][1024]
  const float* gw = (const float*)d_in[2];  // [1000][8192]
  float* out = (float*)d_out;               // [4096*1000] output ++ [4096] winners

  const size_t MB = 1024 * 1024;
  char* ws = (char*)d_ws;
  f16*    xh      = (f16*)(ws);                     // 8 MB
  f16*    kh      = (f16*)(ws + 8 * MB);            // 16 MB
  uint2*  pk      = (uint2*)(ws + 24 * MB);         // 2 MB
  int*    winners = (int*)(ws + 26 * MB);           // 16 KB
  float*  Gt      = (float*)(ws + 26 * MB + 65536); // 32.77 MB
  const size_t need = 26 * MB + 65536 + sizeof(float) * (size_t)HH * OO;
  const bool use_transpose = ws_size >= need;

  // 1) fp32 -> fp16 (+ parallel G transpose tiles)
  int cvt_blocks = BB + HH + (use_transpose ? 8192 : 0);
  cvt_kernel<<<cvt_blocks, 256, 0, stream>>>(x, kw, xh, kh, gw,
                                             use_transpose ? Gt : nullptr);

  // 2) fp16 MFMA GEMM + top-2 keys
  dim3 g(HH / BN, BB / BM);  // (64, 32)
  gemm_top2<<<g, 256, 0, stream>>>(xh, kh, pk);

  // 3) wave-per-row exact fp64 refinement -> winners, fused coalesced gather
  select_kernel<<<BB / 4, 256, 0, stream>>>(x, kw, pk,
                                            use_transpose ? Gt : nullptr,
                                            out, out + (size_t)BB * OO, winners);

  // fallback gather if workspace too small for Gt
  if (!use_transpose) {
    gather_kernel<<<dim3((OO + 255) / 256, BB), 256, 0, stream>>>(gw, winners, out);
  }
}